// Round 4
// baseline (987.104 us; speedup 1.0000x reference)
//
#include <hip/hip_runtime.h>
#include <stdint.h>

// Boolean reservoir: B=128, T=16, N=65536, K=8, IB=256, O=10
#define NN     65536
#define KK     8
#define BB     128
#define TT     16
#define IBITS  256
#define OO     10

#define ZIDX         (NN + IBITS)        // always-zero sentinel entry
#define SBUF_ENTRIES (NN + IBITS + 1)
#define RCHUNKS 512
#define RNODES  128
#define SP_BLOCKS 1024                   // persistent grid: 4 blocks/CU on 256 CUs

// ---------- helpers ----------
__device__ __forceinline__ uint32_t bmask(uint32_t w, int off) {
  return (uint32_t)__builtin_amdgcn_sbfe((int)w, off, 1);  // bit -> full 32b mask
}
// mux(s, hi, lo): per-bit select -> single v_bfi_b32
__device__ __forceinline__ uint32_t mux(uint32_t s, uint32_t hi, uint32_t lo) {
  return ((hi ^ lo) & s) ^ lo;
}

// ---------- Shannon mux-tree over raw truth table, 1 batch-word/thread ----------
template<int D, int BASE> struct Sh1 {
  static __device__ __forceinline__ uint32_t eval(const uint32_t (&L)[8],
                                                  const uint32_t (&xv)[8]) {
    uint32_t lo = Sh1<D - 1, BASE>::eval(L, xv);
    uint32_t hi = Sh1<D - 1, BASE + (1 << (D - 1))>::eval(L, xv);
    return mux(xv[D - 1], hi, lo);
  }
};
template<int BASE> struct Sh1<2, BASE> {
  static __device__ __forceinline__ uint32_t eval(const uint32_t (&L)[8],
                                                  const uint32_t (&xv)[8]) {
    const uint32_t lw = L[BASE >> 5];
    const uint32_t c0 = bmask(lw, (BASE & 31) + 0);
    const uint32_t c1 = bmask(lw, (BASE & 31) + 1);
    const uint32_t c2 = bmask(lw, (BASE & 31) + 2);
    const uint32_t c3 = bmask(lw, (BASE & 31) + 3);
    const uint32_t t0 = mux(xv[0], c1, c0);
    const uint32_t t1 = mux(xv[0], c3, c2);
    return mux(xv[1], t1, t0);
  }
};

// ---------- fused prep: lut pack | madj fold | x pack | state init | ctr zero ----------
#define PB_LUT   2048
#define PB_MADJ  2048
#define PB_X     64
#define PB_STATE 256
#define PREP_BLOCKS (PB_LUT + PB_MADJ + PB_X + PB_STATE)

__global__ __launch_bounds__(256) void prep_kernel(
    const int* __restrict__ lut, const int* __restrict__ adj,
    const int* __restrict__ adjm, const int* __restrict__ x,
    const int* __restrict__ init,
    uint32_t* __restrict__ luttt, int* __restrict__ madj,
    uint32_t* __restrict__ xvecw, uint4* __restrict__ sA, uint4* __restrict__ sB,
    uint32_t* __restrict__ ctrs) {
  const int b = blockIdx.x, t = threadIdx.x;
  if (b < PB_LUT) {
    const int g = b * 256 + t;              // 0 .. 524287
    const int n = g >> 3, w = g & 7;
    const int4* lut4 = (const int4*)lut;
    uint32_t val = 0;
#pragma unroll
    for (int q = 0; q < 8; ++q) {
      int4 v = lut4[n * 64 + w * 8 + q];
      val |= (uint32_t)(v.x & 1) << (4 * q + 0);
      val |= (uint32_t)(v.y & 1) << (4 * q + 1);
      val |= (uint32_t)(v.z & 1) << (4 * q + 2);
      val |= (uint32_t)(v.w & 1) << (4 * q + 3);
    }
    luttt[g] = val;
  } else if (b < PB_LUT + PB_MADJ) {
    const int g = (b - PB_LUT) * 256 + t;   // 0 .. 524287
    int a = adj[g];
    int m = adjm[g] & 1;
    madj[g] = m ? ((a < IBITS) ? a + NN : a) : ZIDX;
  } else if (b < PB_LUT + PB_MADJ + PB_X) {
    const int g = (b - PB_LUT - PB_MADJ) * 256 + t;  // 0 .. 16383
    const int tt = g >> 10, rest = g & 1023, i = rest >> 2, bq = rest & 3;
    uint32_t wv = 0;
#pragma unroll
    for (int bl = 0; bl < 32; ++bl) {
      int bb = bq * 32 + bl;
      wv |= (uint32_t)(x[(bb * TT + tt) * IBITS + i] & 1) << bl;
    }
    xvecw[(tt * IBITS + i) * 4 + bq] = wv;
  } else {
    const int n = (b - PB_LUT - PB_MADJ - PB_X) * 256 + t;
    uint32_t m = 0u - (uint32_t)(init[n] & 1);
    uint4 s = make_uint4(m, m, m, m);
    sA[n] = s;
    if (n < IBITS) {
      uint32_t wv[4] = {0, 0, 0, 0};
#pragma unroll
      for (int bb = 0; bb < BB; ++bb) {
        uint32_t bit = (uint32_t)(x[(bb * TT + 0) * IBITS + n] & 1);
        wv[bb >> 5] |= bit << (bb & 31);
      }
      sA[NN + n] = make_uint4(s.x ^ wv[0], s.y ^ wv[1], s.z ^ wv[2], s.w ^ wv[3]);
    }
    if (n < 512) ctrs[n] = 0;  // barrier counters (32 used, 16-uint stride)
    if (n == 0) {
      uint4 z = make_uint4(0, 0, 0, 0);
      sA[ZIDX] = z;
      sB[ZIDX] = z;
    }
  }
}

// ---------- device-scope grid barrier (SP_BLOCKS blocks, monotonic phase) ----------
__device__ __forceinline__ void grid_barrier(uint32_t* ctrs, uint32_t phase) {
  __syncthreads();  // drains every wave's stores to L2 (vmcnt0 before s_barrier)
  if (threadIdx.x == 0) {
    __threadfence();  // release: L2 writeback to coherence point (covers whole XCD L2)
    atomicAdd(&ctrs[(blockIdx.x & 31) * 16], 1u);  // device-scope by default
  }
  if (threadIdx.x < 32) {
    const uint32_t tgt = phase * (SP_BLOCKS / 32);
    while (__hip_atomic_load(&ctrs[threadIdx.x * 16], __ATOMIC_RELAXED,
                             __HIP_MEMORY_SCOPE_AGENT) < tgt) {
      __builtin_amdgcn_s_sleep(2);
    }
  }
  __syncthreads();
  if (threadIdx.x < 64) __threadfence();  // acquire: invalidate stale L1/L2 (per-CU/XCD op)
  __syncthreads();
}

// ---------- persistent 16-step kernel: meta in registers, grid barrier between steps ----------
__global__ __launch_bounds__(256, 4) void steps_kernel(
    uint32_t* __restrict__ sA, uint32_t* __restrict__ sB,
    const uint32_t* __restrict__ luttt, const int* __restrict__ madj,
    const uint32_t* __restrict__ xvecw, uint32_t* __restrict__ ctrs) {
  const int g = blockIdx.x * 256 + threadIdx.x;  // 0 .. 262143
  const int n = g >> 2, w = g & 3;               // 4 lanes per node -> 16B coalesced gathers
  const int4* madj4 = (const int4*)madj;
  const uint4* lut4v = (const uint4*)luttt;
  int4 a0 = madj4[n * 2 + 0], a1 = madj4[n * 2 + 1];
  uint4 l0 = lut4v[n * 2 + 0], l1 = lut4v[n * 2 + 1];
  uint32_t L[8] = {l0.x, l0.y, l0.z, l0.w, l1.x, l1.y, l1.z, l1.w};
  const int ia[8] = {a0.x, a0.y, a0.z, a0.w, a1.x, a1.y, a1.z, a1.w};
  // variable x_j (weight 2^j) = neighbor k=7-j; precompute byte offsets once
  uint32_t off[8];
#pragma unroll
  for (int j = 0; j < 8; ++j) off[j] = ((uint32_t)ia[7 - j] << 4) + ((uint32_t)w << 2);

  uint32_t* cur = sA;
  uint32_t* nxt = sB;
#pragma unroll 1
  for (int t = 0; t < TT; ++t) {
    // keep L opaque so LICM can't hoist the 256 per-step bit-splats (reg blowup)
#pragma unroll
    for (int i = 0; i < 8; ++i) asm volatile("" : "+v"(L[i]));
    const char* base = (const char*)cur;
    uint32_t xv[8];
#pragma unroll
    for (int j = 0; j < 8; ++j)  // issue x0 first: leaf muxes can start earliest
      xv[j] = *(const uint32_t*)(base + off[j]);
    uint32_t r = Sh1<8, 0>::eval(L, xv);
    nxt[(n << 2) + w] = r;
    if (n < IBITS && t + 1 < TT) {
      // pre-xor'd shadow for next step's gathers (input injection)
      nxt[((NN + n) << 2) + w] = r ^ xvecw[((t + 1) * IBITS + n) * 4 + w];
    }
    uint32_t* tmp = cur; cur = nxt; nxt = tmp;
    if (t + 1 < TT) grid_barrier(ctrs, (uint32_t)(t + 1));
  }
  // after 16 swaps the final state is back in sA
}

// ---------- readout partials: LDS-staged w + state, (b, o-half) threads ----------
__global__ __launch_bounds__(256) void readout_kernel(const uint32_t* __restrict__ statew,
                                                      const float* __restrict__ w,
                                                      float* __restrict__ part) {
  __shared__ uint32_t sw[64 * 4];
  __shared__ float wsm[OO * 64];
  const int c = blockIdx.x;
  const int t = threadIdx.x;
  const int b = t & 127, oh = t >> 7;
  const int word = b >> 5, sh = b & 31;
  float acc[5] = {0.f, 0.f, 0.f, 0.f, 0.f};
  for (int s = 0; s < 2; ++s) {
    const int base = c * RNODES + s * 64;
    __syncthreads();
    sw[t] = statew[base * 4 + t];
#pragma unroll
    for (int r = 0; r < 3; ++r) {
      int idx = r * 256 + t;
      if (idx < OO * 64) wsm[idx] = w[(idx >> 6) * NN + base + (idx & 63)];
    }
    __syncthreads();
#pragma unroll 8
    for (int j = 0; j < 64; ++j) {
      uint32_t m = 0u - ((sw[j * 4 + word] >> sh) & 1u);
#pragma unroll
      for (int q = 0; q < 5; ++q) {
        uint32_t wv = __float_as_uint(wsm[(oh * 5 + q) * 64 + j]) & m;
        acc[q] += __uint_as_float(wv);
      }
    }
  }
#pragma unroll
  for (int q = 0; q < 5; ++q)
    part[(c * BB + b) * OO + oh * 5 + q] = acc[q];
}

// ---------- finalize: block per (b,o), tree-reduce 512 partials ----------
__global__ __launch_bounds__(256) void finalize_kernel(const float* __restrict__ part,
                                                       const float* __restrict__ bias,
                                                       float* __restrict__ out) {
  __shared__ float red[256];
  const int i = blockIdx.x;  // 0 .. BB*OO-1
  const int b = i / OO, o = i % OO;
  const int t = threadIdx.x;
  float s = part[(t * BB + b) * OO + o] + part[((t + 256) * BB + b) * OO + o];
  red[t] = s;
  __syncthreads();
  for (int h = 128; h > 0; h >>= 1) {
    if (t < h) red[t] += red[t + h];
    __syncthreads();
  }
  if (t == 0) out[b * OO + o] = 1.f / (1.f + __expf(-(red[0] + bias[o])));
}

// ---------- launch ----------
extern "C" void kernel_launch(void* const* d_in, const int* in_sizes, int n_in,
                              void* d_out, int out_size, void* d_ws, size_t ws_size,
                              hipStream_t stream) {
  const int* x    = (const int*)d_in[0];
  const int* adj  = (const int*)d_in[1];
  const int* adjm = (const int*)d_in[2];
  const int* lut  = (const int*)d_in[3];
  const int* init = (const int*)d_in[4];
  // d_in[5] = w_in (arange(IB); folded into the shadow scheme)
  const float* wro = (const float*)d_in[6];
  const float* bro = (const float*)d_in[7];
  float* out = (float*)d_out;

  char* ws = (char*)d_ws;
  const size_t SBUF = (size_t)SBUF_ENTRIES * 16;
  uint4* sA        = (uint4*)(ws);
  uint4* sB        = (uint4*)(ws + SBUF);
  uint32_t* xvecw  = (uint32_t*)(ws + 2 * SBUF);
  uint32_t* luttt  = (uint32_t*)(ws + 2 * SBUF + (size_t)TT * IBITS * 16);
  int* madj        = (int*)(ws + 2 * SBUF + (size_t)TT * IBITS * 16 + (size_t)NN * 32);
  float* part      = (float*)(ws + 2 * SBUF + (size_t)TT * IBITS * 16 + (size_t)NN * 64);
  uint32_t* ctrs   = (uint32_t*)(ws + 2 * SBUF + (size_t)TT * IBITS * 16 + (size_t)NN * 64
                                 + (size_t)RCHUNKS * BB * OO * 4);

  hipLaunchKernelGGL(prep_kernel, dim3(PREP_BLOCKS), dim3(256), 0, stream,
                     lut, adj, adjm, x, init, luttt, madj, xvecw, sA, sB, ctrs);

  hipLaunchKernelGGL(steps_kernel, dim3(SP_BLOCKS), dim3(256), 0, stream,
                     (uint32_t*)sA, (uint32_t*)sB, luttt, madj, xvecw, ctrs);

  hipLaunchKernelGGL(readout_kernel, dim3(RCHUNKS), dim3(256), 0, stream,
                     (const uint32_t*)sA, wro, part);
  hipLaunchKernelGGL(finalize_kernel, dim3(BB * OO), dim3(256), 0, stream, part, bro, out);
}

// Round 5
// 287.934 us; speedup vs baseline: 3.4282x; 3.4282x over previous
//
#include <hip/hip_runtime.h>
#include <stdint.h>

// Boolean reservoir: B=128, T=16, N=65536, K=8, IB=256, O=10
#define NN     65536
#define KK     8
#define BB     128
#define TT     16
#define IBITS  256
#define OO     10

#define ZIDX         (NN + IBITS)        // always-zero sentinel entry
#define SBUF_ENTRIES (NN + IBITS + 1)
#define RCHUNKS 512
#define RNODES  128

// ---------- helpers ----------
__device__ __forceinline__ uint32_t bmask(uint32_t w, int off) {
  return (uint32_t)__builtin_amdgcn_sbfe((int)w, off, 1);  // bit -> full 32b mask
}
// mux(s, hi, lo): per-bit select -> single v_bfi_b32
__device__ __forceinline__ uint32_t mux(uint32_t s, uint32_t hi, uint32_t lo) {
  return ((hi ^ lo) & s) ^ lo;
}

// ---------- Shannon mux-tree over raw truth table, 1 batch-word/thread ----------
template<int D, int BASE> struct Sh1 {
  static __device__ __forceinline__ uint32_t eval(const uint32_t (&L)[8],
                                                  const uint32_t (&xv)[8]) {
    uint32_t lo = Sh1<D - 1, BASE>::eval(L, xv);
    uint32_t hi = Sh1<D - 1, BASE + (1 << (D - 1))>::eval(L, xv);
    return mux(xv[D - 1], hi, lo);
  }
};
template<int BASE> struct Sh1<2, BASE> {
  static __device__ __forceinline__ uint32_t eval(const uint32_t (&L)[8],
                                                  const uint32_t (&xv)[8]) {
    const uint32_t lw = L[BASE >> 5];
    const uint32_t c0 = bmask(lw, (BASE & 31) + 0);
    const uint32_t c1 = bmask(lw, (BASE & 31) + 1);
    const uint32_t c2 = bmask(lw, (BASE & 31) + 2);
    const uint32_t c3 = bmask(lw, (BASE & 31) + 3);
    const uint32_t t0 = mux(xv[0], c1, c0);
    const uint32_t t1 = mux(xv[0], c3, c2);
    return mux(xv[1], t1, t0);
  }
};

// ---------- fused prep: lut pack | madj fold | x pack | state init ----------
#define PB_LUT   2048
#define PB_MADJ  2048
#define PB_X     64
#define PB_STATE 256
#define PREP_BLOCKS (PB_LUT + PB_MADJ + PB_X + PB_STATE)

__global__ __launch_bounds__(256) void prep_kernel(
    const int* __restrict__ lut, const int* __restrict__ adj,
    const int* __restrict__ adjm, const int* __restrict__ x,
    const int* __restrict__ init,
    uint32_t* __restrict__ luttt, int* __restrict__ madj,
    uint32_t* __restrict__ xvecw, uint4* __restrict__ sA, uint4* __restrict__ sB) {
  const int b = blockIdx.x, t = threadIdx.x;
  if (b < PB_LUT) {
    // pack truth table: bit i of node n's 256-bit table = lut[n][i] & 1
    const int g = b * 256 + t;              // 0 .. 524287
    const int n = g >> 3, w = g & 7;
    const int4* lut4 = (const int4*)lut;
    uint32_t val = 0;
#pragma unroll
    for (int q = 0; q < 8; ++q) {
      int4 v = lut4[n * 64 + w * 8 + q];
      val |= (uint32_t)(v.x & 1) << (4 * q + 0);
      val |= (uint32_t)(v.y & 1) << (4 * q + 1);
      val |= (uint32_t)(v.z & 1) << (4 * q + 2);
      val |= (uint32_t)(v.w & 1) << (4 * q + 3);
    }
    luttt[g] = val;
  } else if (b < PB_LUT + PB_MADJ) {
    // fold adj + mask + shadow-remap into one index (zero-sentinel for masked)
    const int g = (b - PB_LUT) * 256 + t;   // 0 .. 524287
    int a = adj[g];
    int m = adjm[g] & 1;
    madj[g] = m ? ((a < IBITS) ? a + NN : a) : ZIDX;
  } else if (b < PB_LUT + PB_MADJ + PB_X) {
    // pack x: (B,T,IB) -> per (t,i) 4 batch words
    const int g = (b - PB_LUT - PB_MADJ) * 256 + t;  // 0 .. 16383
    const int tt = g >> 10, rest = g & 1023, i = rest >> 2, bq = rest & 3;
    uint32_t wv = 0;
#pragma unroll
    for (int bl = 0; bl < 32; ++bl) {
      int bb = bq * 32 + bl;
      wv |= (uint32_t)(x[(bb * TT + tt) * IBITS + i] & 1) << bl;
    }
    xvecw[(tt * IBITS + i) * 4 + bq] = wv;
  } else {
    // initial state broadcast + t=0 xor'd shadow + zero sentinels
    const int n = (b - PB_LUT - PB_MADJ - PB_X) * 256 + t;
    uint32_t m = 0u - (uint32_t)(init[n] & 1);
    uint4 s = make_uint4(m, m, m, m);
    sA[n] = s;
    if (n < IBITS) {
      uint32_t wv[4] = {0, 0, 0, 0};
#pragma unroll
      for (int bb = 0; bb < BB; ++bb) {
        uint32_t bit = (uint32_t)(x[(bb * TT + 0) * IBITS + n] & 1);
        wv[bb >> 5] |= bit << (bb & 31);
      }
      sA[NN + n] = make_uint4(s.x ^ wv[0], s.y ^ wv[1], s.z ^ wv[2], s.w ^ wv[3]);
    }
    if (n == 0) {
      uint4 z = make_uint4(0, 0, 0, 0);
      sA[ZIDX] = z;
      sB[ZIDX] = z;
    }
  }
}

// ---------- one reservoir step: 1 batch-word/thread, Shannon mux-tree ----------
__global__ __launch_bounds__(256) void step_kernel(const uint32_t* __restrict__ sinw,
                                                   uint32_t* __restrict__ soutw,
                                                   const uint4* __restrict__ luttt,
                                                   const int* __restrict__ madj,
                                                   const uint32_t* __restrict__ xnextw) {
  const int g = blockIdx.x * 256 + threadIdx.x;  // 0 .. 4*NN-1
  const int n = g >> 2, w = g & 3;               // 4 lanes/node -> 16B coalesced gathers
  const int4* madj4 = (const int4*)madj;
  int4 a0 = madj4[n * 2 + 0], a1 = madj4[n * 2 + 1];
  uint4 l0 = luttt[n * 2 + 0], l1 = luttt[n * 2 + 1];
  const int ia[8] = {a0.x, a0.y, a0.z, a0.w, a1.x, a1.y, a1.z, a1.w};
  uint32_t xv[8];
#pragma unroll
  for (int k = 7; k >= 0; --k) {
    // neighbor k has weight 2^(7-k) -> Shannon variable x_{7-k}; x0,x1 load first
    xv[7 - k] = sinw[(ia[k] << 2) + w];
  }
  const uint32_t L[8] = {l0.x, l0.y, l0.z, l0.w, l1.x, l1.y, l1.z, l1.w};
  uint32_t r = Sh1<8, 0>::eval(L, xv);
  soutw[(n << 2) + w] = r;
  if (xnextw != nullptr && n < IBITS) {
    soutw[((NN + n) << 2) + w] = r ^ xnextw[(n << 2) + w];  // next step's shadow
  }
}

// ---------- readout partials: LDS-staged w + state, (b, o-half) threads ----------
__global__ __launch_bounds__(256) void readout_kernel(const uint32_t* __restrict__ statew,
                                                      const float* __restrict__ w,
                                                      float* __restrict__ part) {
  __shared__ uint32_t sw[64 * 4];
  __shared__ float wsm[OO * 64];
  const int c = blockIdx.x;
  const int t = threadIdx.x;
  const int b = t & 127, oh = t >> 7;
  const int word = b >> 5, sh = b & 31;
  float acc[5] = {0.f, 0.f, 0.f, 0.f, 0.f};
  for (int s = 0; s < 2; ++s) {
    const int base = c * RNODES + s * 64;
    __syncthreads();
    sw[t] = statew[base * 4 + t];
#pragma unroll
    for (int r = 0; r < 3; ++r) {
      int idx = r * 256 + t;
      if (idx < OO * 64) wsm[idx] = w[(idx >> 6) * NN + base + (idx & 63)];
    }
    __syncthreads();
#pragma unroll 8
    for (int j = 0; j < 64; ++j) {
      uint32_t m = 0u - ((sw[j * 4 + word] >> sh) & 1u);
#pragma unroll
      for (int q = 0; q < 5; ++q) {
        uint32_t wv = __float_as_uint(wsm[(oh * 5 + q) * 64 + j]) & m;
        acc[q] += __uint_as_float(wv);
      }
    }
  }
#pragma unroll
  for (int q = 0; q < 5; ++q)
    part[(c * BB + b) * OO + oh * 5 + q] = acc[q];
}

// ---------- finalize: block per (b,o), tree-reduce 512 partials ----------
__global__ __launch_bounds__(256) void finalize_kernel(const float* __restrict__ part,
                                                       const float* __restrict__ bias,
                                                       float* __restrict__ out) {
  __shared__ float red[256];
  const int i = blockIdx.x;  // 0 .. BB*OO-1
  const int b = i / OO, o = i % OO;
  const int t = threadIdx.x;
  float s = part[(t * BB + b) * OO + o] + part[((t + 256) * BB + b) * OO + o];
  red[t] = s;
  __syncthreads();
  for (int h = 128; h > 0; h >>= 1) {
    if (t < h) red[t] += red[t + h];
    __syncthreads();
  }
  if (t == 0) out[b * OO + o] = 1.f / (1.f + __expf(-(red[0] + bias[o])));
}

// ---------- launch ----------
extern "C" void kernel_launch(void* const* d_in, const int* in_sizes, int n_in,
                              void* d_out, int out_size, void* d_ws, size_t ws_size,
                              hipStream_t stream) {
  const int* x    = (const int*)d_in[0];
  const int* adj  = (const int*)d_in[1];
  const int* adjm = (const int*)d_in[2];
  const int* lut  = (const int*)d_in[3];
  const int* init = (const int*)d_in[4];
  // d_in[5] = w_in (arange(IB); folded into the shadow scheme)
  const float* wro = (const float*)d_in[6];
  const float* bro = (const float*)d_in[7];
  float* out = (float*)d_out;

  char* ws = (char*)d_ws;
  const size_t SBUF = (size_t)SBUF_ENTRIES * 16;
  uint4* sA        = (uint4*)(ws);
  uint4* sB        = (uint4*)(ws + SBUF);
  uint32_t* xvecw  = (uint32_t*)(ws + 2 * SBUF);
  uint32_t* luttt  = (uint32_t*)(ws + 2 * SBUF + (size_t)TT * IBITS * 16);
  int* madj        = (int*)(ws + 2 * SBUF + (size_t)TT * IBITS * 16 + (size_t)NN * 32);
  float* part      = (float*)(ws + 2 * SBUF + (size_t)TT * IBITS * 16 + (size_t)NN * 64);

  hipLaunchKernelGGL(prep_kernel, dim3(PREP_BLOCKS), dim3(256), 0, stream,
                     lut, adj, adjm, x, init, luttt, madj, xvecw, sA, sB);

  for (int t = 0; t < TT; ++t) {
    const uint32_t* sin = (const uint32_t*)((t & 1) ? sB : sA);
    uint32_t* sout      = (uint32_t*)((t & 1) ? sA : sB);
    const uint32_t* xn  = (t + 1 < TT) ? (xvecw + (size_t)(t + 1) * IBITS * 4) : nullptr;
    hipLaunchKernelGGL(step_kernel, dim3((NN * 4) / 256), dim3(256), 0, stream,
                       sin, sout, (const uint4*)luttt, madj, xn);
  }
  // T=16 steps: final state in sA
  hipLaunchKernelGGL(readout_kernel, dim3(RCHUNKS), dim3(256), 0, stream,
                     (const uint32_t*)sA, wro, part);
  hipLaunchKernelGGL(finalize_kernel, dim3(BB * OO), dim3(256), 0, stream, part, bro, out);
}